// Round 4
// baseline (212.682 us; speedup 1.0000x reference)
//
#include <hip/hip_runtime.h>

// Dice coefficient: argmax over C=4 classes per pixel + histogram counts.
// Shapes fixed by the problem: B=32, C=4, H=W=512.
constexpr int kHW = 512 * 512;   // 262144 pixels per plane (65536 float4-groups)
constexpr int kC  = 4;
constexpr int kBlocks = 2048;    // 64 blocks per batch plane

// ws layout: per-block packed partials, u64[3] per block (predp, truep, tpp).
// Fully overwritten every launch -> no init needed despite 0xAA poison.

__device__ __forceinline__ void do_group(const float4& v0, const float4& v1,
                                         const float4& v2, const float4& v3,
                                         const int4& t,
                                         unsigned long long& predp,
                                         unsigned long long& truep,
                                         unsigned long long& tpp) {
    // First-max-wins argmax (strict >) matches jnp.argmax semantics.
    #define DO_PIXEL(f, tf)                                        \
    {                                                              \
        int   pred = 0;                                            \
        float best = v0.f;                                         \
        if (v1.f > best) { best = v1.f; pred = 1; }                \
        if (v2.f > best) { best = v2.f; pred = 2; }                \
        if (v3.f > best) { best = v3.f; pred = 3; }                \
        predp += 1ull << (pred << 4);                              \
        truep += 1ull << (t.tf << 4);                              \
        if (pred == t.tf) tpp += 1ull << (pred << 4);              \
    }
    DO_PIXEL(x, x) DO_PIXEL(y, y) DO_PIXEL(z, z) DO_PIXEL(w, w)
    #undef DO_PIXEL
}

// 2048 blocks x 256 threads x 4 groups/thread = 2,097,152 groups (exact cover).
// Each block covers 1024 consecutive groups in one batch plane (b uniform).
// Software-pipelined: stage k+1's 5 loads issue before stage k's compute,
// keeping ~10 x 16B loads in flight per thread (fights load-sinking / low MLP).
__global__ __launch_bounds__(256)
void dice_count_kernel(const int* __restrict__ tm, const float* __restrict__ outp,
                       unsigned long long* __restrict__ part) {
    const int b  = blockIdx.x >> 6;                          // 64 blocks / plane
    const int g0 = ((blockIdx.x & 63) << 10) + threadIdx.x;  // group idx in plane

    const float* pb = outp + (size_t)b * kC * kHW;
    const int*   tb = tm   + (size_t)b * kHW;

    float4 a0, a1, a2, a3, b0, b1, b2, b3;
    int4   ta, tbm;

    #define LOAD(k, r0, r1, r2, r3, rt)                    \
    {                                                      \
        const int rem = (g0 + ((k) << 8)) << 2;            \
        r0 = *(const float4*)(pb + rem);                   \
        r1 = *(const float4*)(pb + kHW + rem);             \
        r2 = *(const float4*)(pb + 2 * kHW + rem);         \
        r3 = *(const float4*)(pb + 3 * kHW + rem);         \
        rt = *(const int4*)(tb + rem);                     \
    }

    unsigned long long predp = 0, truep = 0, tpp = 0;

    LOAD(0, a0, a1, a2, a3, ta)
    LOAD(1, b0, b1, b2, b3, tbm)
    do_group(a0, a1, a2, a3, ta, predp, truep, tpp);
    LOAD(2, a0, a1, a2, a3, ta)
    do_group(b0, b1, b2, b3, tbm, predp, truep, tpp);
    LOAD(3, b0, b1, b2, b3, tbm)
    do_group(a0, a1, a2, a3, ta, predp, truep, tpp);
    do_group(b0, b1, b2, b3, tbm, predp, truep, tpp);
    #undef LOAD

    // Wave-64 butterfly reduction (fields <= 1024/wave, fits u16).
    for (int off = 32; off > 0; off >>= 1) {
        predp += __shfl_down(predp, off);
        truep += __shfl_down(truep, off);
        tpp   += __shfl_down(tpp, off);
    }

    __shared__ unsigned long long s[3][4];
    const int lane = threadIdx.x & 63;
    const int wave = threadIdx.x >> 6;
    if (lane == 0) { s[0][wave] = predp; s[1][wave] = truep; s[2][wave] = tpp; }
    __syncthreads();

    if (threadIdx.x == 0) {
        // Block totals <= 4096 per u16 field. Plain stores, no atomics/init.
        unsigned long long* p = part + (size_t)blockIdx.x * 3;
        p[0] = s[0][0] + s[0][1] + s[0][2] + s[0][3];
        p[1] = s[1][0] + s[1][1] + s[1][2] + s[1][3];
        p[2] = s[2][0] + s[2][1] + s[2][2] + s[2][3];
    }
}

// One block, 256 threads: sum 2048 packed partials (8/thread, packed sums
// <= 8*4096 = 32768 — still fits u16), unpack to u32, reduce, divide.
__global__ __launch_bounds__(256)
void dice_final_kernel(const unsigned long long* __restrict__ part,
                       float* __restrict__ out) {
    unsigned long long P = 0, T = 0, Q = 0;
    #pragma unroll
    for (int i = 0; i < 8; ++i) {
        const unsigned long long* p = part + ((size_t)threadIdx.x + (i << 8)) * 3;
        P += p[0]; T += p[1]; Q += p[2];
    }

    unsigned pc[4], tc[4], qc[4];
    #pragma unroll
    for (int c = 0; c < 4; ++c) {
        pc[c] = (unsigned)((P >> (c * 16)) & 0xFFFF);
        tc[c] = (unsigned)((T >> (c * 16)) & 0xFFFF);
        qc[c] = (unsigned)((Q >> (c * 16)) & 0xFFFF);
    }
    for (int off = 32; off > 0; off >>= 1) {
        #pragma unroll
        for (int c = 0; c < 4; ++c) {
            pc[c] += __shfl_down(pc[c], off);
            tc[c] += __shfl_down(tc[c], off);
            qc[c] += __shfl_down(qc[c], off);
        }
    }

    __shared__ unsigned s[12][4];
    const int lane = threadIdx.x & 63;
    const int wave = threadIdx.x >> 6;
    if (lane == 0) {
        #pragma unroll
        for (int c = 0; c < 4; ++c) {
            s[c][wave]     = pc[c];
            s[4 + c][wave] = tc[c];
            s[8 + c][wave] = qc[c];
        }
    }
    __syncthreads();

    if (threadIdx.x >= 1 && threadIdx.x < 4) {   // classes 1..3 (skip background)
        const int c = (int)threadIdx.x;
        const float pcnt = (float)(s[c][0] + s[c][1] + s[c][2] + s[c][3]);
        const float tcnt = (float)(s[4 + c][0] + s[4 + c][1] + s[4 + c][2] + s[4 + c][3]);
        const float tp   = (float)(s[8 + c][0] + s[8 + c][1] + s[8 + c][2] + s[8 + c][3]);
        out[c - 1] = 2.0f * tp / (pcnt + tcnt);
    }
}

extern "C" void kernel_launch(void* const* d_in, const int* in_sizes, int n_in,
                              void* d_out, int out_size, void* d_ws, size_t ws_size,
                              hipStream_t stream) {
    const int*   tm = (const int*)d_in[0];    // true_masks [B,H,W] int32
    const float* op = (const float*)d_in[1];  // out        [B,C,H,W] f32
    unsigned long long* part = (unsigned long long*)d_ws;

    dice_count_kernel<<<kBlocks, 256, 0, stream>>>(tm, op, part);
    dice_final_kernel<<<1, 256, 0, stream>>>(part, (float*)d_out);
}